// Round 1
// 706.629 us; speedup vs baseline: 1.3419x; 1.3419x over previous
//
#include <hip/hip_runtime.h>

#define Hd 256
#define Wd 256
#define HW 65536
#define C 64
#define B 8
#define M 16
#define NDEPTH 4
#define NMLP 128

typedef __attribute__((ext_vector_type(8))) __bf16 bf16x8;
typedef __attribute__((ext_vector_type(4))) float f32x4;

// split fp32 -> bf16 hi (RNE) + bf16 lo (RNE of residual); pack 8 values into
// one uint4 per plane (k-contiguous 16B cell for ds_read_b128 MFMA fragments).
__device__ inline void split_pack8(const float* v, uint4& hq, uint4& lq) {
    unsigned hw[4], lw[4];
#pragma unroll
    for (int i = 0; i < 4; ++i) {
        float a = v[2 * i], bb = v[2 * i + 1];
        unsigned ua = __float_as_uint(a);
        unsigned ha = (ua + 0x7fffu + ((ua >> 16) & 1u)) & 0xffff0000u;
        float ra = a - __uint_as_float(ha);
        unsigned ural = __float_as_uint(ra);
        unsigned la = (ural + 0x7fffu + ((ural >> 16) & 1u)) >> 16;
        unsigned ub = __float_as_uint(bb);
        unsigned hb = (ub + 0x7fffu + ((ub >> 16) & 1u)) & 0xffff0000u;
        float rb = bb - __uint_as_float(hb);
        unsigned urbl = __float_as_uint(rb);
        unsigned lb = (urbl + 0x7fffu + ((urbl >> 16) & 1u)) >> 16;
        hw[i] = (ha >> 16) | (hb & 0xffff0000u);
        lw[i] = la | (lb << 16);
    }
    hq = make_uint4(hw[0], hw[1], hw[2], hw[3]);
    lq = make_uint4(lw[0], lw[1], lw[2], lw[3]);
}

// ---------------- twiddle table ----------------
__global__ void k_table(float2* __restrict__ tab) {
    int t = threadIdx.x;
    double a = (6.283185307179586476925286766559 / 256.0) * (double)t;
    tab[t] = make_float2((float)cos(a), (float)sin(a));
}

// ---------------- once: trig, trigFT, w1T, wwT_all ----------------
__global__ void k_prep0(const float2* __restrict__ tab, const float* __restrict__ fc1w,
                        const float* __restrict__ ww,
                        float* __restrict__ trig, float* __restrict__ trigFT,
                        float* __restrict__ w1T, float* __restrict__ wwT_all) {
    int blk = blockIdx.x, t = threadIdx.x;
    if (blk < 32) {                    // trig[kk][x]: cos kk<16, +sin kk>=16
        int k = blk & 15;
        float2 e = tab[(k * t) & 255];
        trig[blk * 256 + t] = (blk < 16) ? e.x : e.y;
    } else if (blk < 64) {             // trigFT[y][kk]: cos kk<16, -sin kk>=16
        int f = (blk - 32) * 256 + t;
        int y = f >> 5, kk = f & 31;
        float2 e = tab[((kk & 15) * y) & 255];
        trigFT[f] = (kk < 16) ? e.x : -e.y;
    } else if (blk < 96) {             // w1T[i][m] = fc1w[m][i]
        int f = (blk - 64) * 256 + t;
        int i = f >> 7, m = f & 127;
        w1T[f] = fc1w[m * 64 + i];
    } else {                           // wwT_all[d][i][o] = ww[d][o][i]
        int f = (blk - 96) * 256 + t;
        int d = f >> 12, r = f & 4095;
        int i = r >> 6, o = r & 63;
        wwT_all[f] = ww[d * 4096 + o * 64 + i];
    }
}

// ---------------- fc0 ----------------
__global__ void k_fc0(const float* __restrict__ x, const float* __restrict__ w,
                      const float* __restrict__ bias, float* __restrict__ h) {
    int p = blockIdx.x * 256 + threadIdx.x;
    int b = p >> 16, pix = p & 65535;
    float x0 = x[(b * 3 + 0) * HW + pix];
    float x1 = x[(b * 3 + 1) * HW + pix];
    float x2 = x[(b * 3 + 2) * HW + pix];
    for (int o = 0; o < C; ++o) {
        float v = bias[o];
        v = fmaf(w[o * 3 + 0], x0, v);
        v = fmaf(w[o * 3 + 1], x1, v);
        v = fmaf(w[o * 3 + 2], x2, v);
        h[(b * C + o) * HW + pix] = v;
    }
}

// ---------------- forward y-DFT as GEMM (unchanged from R12) ----------------
__global__ __launch_bounds__(128, 2)
void k_fwd_y(const float* __restrict__ h, const float* __restrict__ trigFT,
             float* __restrict__ T1F) {
    __shared__ float sH[32 * 256];   // 32 KB
    __shared__ float sE[32 * 32];    // 4 KB
    int bc = blockIdx.x, t = threadIdx.x;
    int rg = t >> 5, cg = t & 31;
    float acc[8][8];
#pragma unroll
    for (int io = 0; io < 8; ++io)
#pragma unroll
        for (int ix = 0; ix < 8; ++ix) acc[io][ix] = 0.f;
    float4* sH4 = (float4*)sH;
    float4* sE4 = (float4*)sE;
    for (int ph = 0; ph < 8; ++ph) {
#pragma unroll
        for (int p = 0; p < 16; ++p) {
            int f = t + p * 128;
            sH4[f] = *(const float4*)(h + (size_t)bc * HW + ph * 32 * 256 + f * 4);
        }
#pragma unroll
        for (int p = 0; p < 2; ++p) {
            int f = t + p * 128;
            sE4[f] = *(const float4*)(trigFT + ph * 1024 + f * 4);
        }
        __syncthreads();
#pragma unroll 4
        for (int yy = 0; yy < 32; ++yy) {
            float4 e0 = sE4[yy * 8 + rg * 2], e1 = sE4[yy * 8 + rg * 2 + 1];
            float4 h0 = sH4[yy * 64 + cg];
            float4 h1 = sH4[yy * 64 + 32 + cg];
            float ae[8] = {e0.x, e0.y, e0.z, e0.w, e1.x, e1.y, e1.z, e1.w};
            float ah[8] = {h0.x, h0.y, h0.z, h0.w, h1.x, h1.y, h1.z, h1.w};
#pragma unroll
            for (int io = 0; io < 8; ++io)
#pragma unroll
                for (int ix = 0; ix < 8; ++ix)
                    acc[io][ix] = fmaf(ae[io], ah[ix], acc[io][ix]);
        }
        __syncthreads();
    }
#pragma unroll
    for (int io = 0; io < 8; ++io) {
        float* dst = T1F + (size_t)bc * 8192 + (rg * 8 + io) * 256;
        float4 v0, v1;
        v0.x = acc[io][0]; v0.y = acc[io][1]; v0.z = acc[io][2]; v0.w = acc[io][3];
        v1.x = acc[io][4]; v1.y = acc[io][5]; v1.z = acc[io][6]; v1.w = acc[io][7];
        *(float4*)(dst + cg * 4) = v0;
        *(float4*)(dst + 128 + cg * 4) = v1;
    }
}

// ---------------- forward x-DFT (unchanged from R12) ----------------
__global__ __launch_bounds__(256, 2)
void k_fwd_x(const float* __restrict__ T1F, const float* __restrict__ trig,
             float2* __restrict__ X) {
    __shared__ float sT[32 * 260];
    __shared__ float sG[32 * 260];
    int bc = blockIdx.x, t = threadIdx.x;
#pragma unroll
    for (int p = 0; p < 8; ++p) {
        int f = t + p * 256;
        int row = f >> 6, seg = f & 63;
        ((float4*)(sT + row * 260))[seg] = *(const float4*)(T1F + (size_t)bc * 8192 + f * 4);
        ((float4*)(sG + row * 260))[seg] = *(const float4*)(trig + row * 256 + seg * 4);
    }
    __syncthreads();
    int ky = t >> 4, kx = t & 15;
    const float* Tr = sT + ky * 260;
    const float* Ti = sT + (16 + ky) * 260;
    const float* Cs = sG + kx * 260;
    const float* Sn = sG + (16 + kx) * 260;
    float xr0 = 0.f, xi0 = 0.f, xr1 = 0.f, xi1 = 0.f;
    for (int q = 0; q < 64; q += 2) {
        float4 tr = *(const float4*)(Tr + q * 4);
        float4 ti = *(const float4*)(Ti + q * 4);
        float4 cs = *(const float4*)(Cs + q * 4);
        float4 sn = *(const float4*)(Sn + q * 4);
        xr0 = fmaf(tr.x, cs.x, xr0); xr0 = fmaf(ti.x, sn.x, xr0);
        xi0 = fmaf(ti.x, cs.x, xi0); xi0 = fmaf(-tr.x, sn.x, xi0);
        xr0 = fmaf(tr.y, cs.y, xr0); xr0 = fmaf(ti.y, sn.y, xr0);
        xi0 = fmaf(ti.y, cs.y, xi0); xi0 = fmaf(-tr.y, sn.y, xi0);
        xr0 = fmaf(tr.z, cs.z, xr0); xr0 = fmaf(ti.z, sn.z, xr0);
        xi0 = fmaf(ti.z, cs.z, xi0); xi0 = fmaf(-tr.z, sn.z, xi0);
        xr0 = fmaf(tr.w, cs.w, xr0); xr0 = fmaf(ti.w, sn.w, xr0);
        xi0 = fmaf(ti.w, cs.w, xi0); xi0 = fmaf(-tr.w, sn.w, xi0);
        float4 tr1 = *(const float4*)(Tr + q * 4 + 4);
        float4 ti1 = *(const float4*)(Ti + q * 4 + 4);
        float4 cs1 = *(const float4*)(Cs + q * 4 + 4);
        float4 sn1 = *(const float4*)(Sn + q * 4 + 4);
        xr1 = fmaf(tr1.x, cs1.x, xr1); xr1 = fmaf(ti1.x, sn1.x, xr1);
        xi1 = fmaf(ti1.x, cs1.x, xi1); xi1 = fmaf(-tr1.x, sn1.x, xi1);
        xr1 = fmaf(tr1.y, cs1.y, xr1); xr1 = fmaf(ti1.y, sn1.y, xr1);
        xi1 = fmaf(ti1.y, cs1.y, xi1); xi1 = fmaf(-tr1.y, sn1.y, xi1);
        xr1 = fmaf(tr1.z, cs1.z, xr1); xr1 = fmaf(ti1.z, sn1.z, xr1);
        xi1 = fmaf(ti1.z, cs1.z, xi1); xi1 = fmaf(-tr1.z, sn1.z, xi1);
        xr1 = fmaf(tr1.w, cs1.w, xr1); xr1 = fmaf(ti1.w, sn1.w, xr1);
        xi1 = fmaf(ti1.w, cs1.w, xi1); xi1 = fmaf(-tr1.w, sn1.w, xi1);
    }
    X[bc * 256 + t] = make_float2(xr0 + xr1, xi0 + xi1);
}

// ---------------- mode mixing (unchanged) ----------------
__global__ __launch_bounds__(256, 2)
void k_mix(const float2* __restrict__ X, const float* __restrict__ wre,
           const float* __restrict__ wim, float2* __restrict__ Y) {
    int o = blockIdx.x >> 2;
    int bq = blockIdx.x & 3;
    int m = threadIdx.x;
    int b0 = bq * 2, b1 = bq * 2 + 1;
    float yr0 = 0.f, yi0 = 0.f, yr1 = 0.f, yi1 = 0.f;
    for (int i = 0; i < C; ++i) {
        float wr = wre[(i * C + o) * 256 + m];
        float wi = wim[(i * C + o) * 256 + m];
        float2 x0 = X[(b0 * C + i) * 256 + m];
        float2 x1 = X[(b1 * C + i) * 256 + m];
        yr0 = fmaf(x0.x, wr, fmaf(-x0.y, wi, yr0));
        yi0 = fmaf(x0.x, wi, fmaf(x0.y, wr, yi0));
        yr1 = fmaf(x1.x, wr, fmaf(-x1.y, wi, yr1));
        yi1 = fmaf(x1.x, wi, fmaf(x1.y, wr, yi1));
    }
    Y[(b0 * C + o) * 256 + m] = make_float2(yr0, yi0);
    Y[(b1 * C + o) * 256 + m] = make_float2(yr1, yi1);
}

// ---------------- fused inverse-y + Gq production (unchanged) ----------------
__global__ __launch_bounds__(256, 2)
void k_invy(const float2* __restrict__ Y, const float2* __restrict__ tab,
            float* __restrict__ Gq) {
    __shared__ float2 st[256];
    int blk = blockIdx.x;              // 8b x 4pg x 16yt
    int yt = blk & 15, pg = (blk >> 4) & 3, b = blk >> 6;
    int t = threadIdx.x;
    st[t] = tab[t];
    int o = t & 63, kx = pg * 4 + (t >> 6);
    __syncthreads();
    float sc = (kx == 0 ? 1.0f : 2.0f) * (1.0f / 65536.0f);
    float yr[16], yi[16];
    const float2* yp = Y + (size_t)(b * 64 + o) * 256 + kx;
#pragma unroll
    for (int ky = 0; ky < 16; ++ky) {
        float2 v = yp[ky * 16];
        yr[ky] = v.x * sc;
        yi[ky] = v.y * sc;
    }
    int y0 = yt * 16;
    for (int yy = 0; yy < 16; ++yy) {
        int y = y0 + yy;
        float re = 0.f, im = 0.f;
#pragma unroll
        for (int ky = 0; ky < 16; ++ky) {
            float2 e = st[(ky * y) & 255];
            re = fmaf(yr[ky], e.x, re);
            re = fmaf(-yi[ky], e.y, re);
            im = fmaf(yr[ky], e.y, im);
            im = fmaf(yi[ky], e.x, im);
        }
        float* gp = Gq + (size_t)(b * 256 + y) * 32 * 64 + o;
        gp[kx * 64] = re;
        gp[(16 + kx) * 64] = -im;
    }
}

// ---------------- k_final: split-bf16 MFMA augmented GEMM ----------------
// R14: MfmaUtil was 0.0 everywhere — fp32 VALU GEMM capped at ~54% of 157 TF.
// D = Ah*Bh + Ah*Bl + Al*Bh on v_mfma_f32_16x16x32_bf16 (no fp32 MFMA on CDNA4).
// LDS cells [kc][col][8k] (16B) -> one ds_read_b128 per fragment, bank-start
// 4*(l&15) = conflict-free. Staging: k-run-per-thread strided dword loads
// (coalesced over x/o across lanes) + split_pack8. 24 KB LDS -> 6 blocks/CU.
__global__ __launch_bounds__(256, 4)
void k_final(float* __restrict__ h, const float* __restrict__ Gq,
             const float* __restrict__ wwT, const float* __restrict__ wb,
             const float* __restrict__ trig) {
    __shared__ uint4 sHh[512], sHl[512];   // [kc(4)][x(128)] 16 KB
    __shared__ uint4 sWh[256], sWl[256];   // [kc(4)][o(64)]   8 KB
    int blk = blockIdx.x;              // b(8) * y(256) * xq(2), xq fastest
    int xq = blk & 1, y = (blk >> 1) & 255, b = blk >> 9;
    int x0 = xq * 128;
    int t = threadIdx.x;
    int xs = t & 127, half = t >> 7;   // H staging: thread owns x=xs, k-run half*16..+15
    int os = t & 63, q = t >> 6;       // W staging: thread owns o=os, k-run q*8..+7
    int w = t >> 6, l = t & 63;        // wave w owns o-rows [w*16, w*16+16)
    int lr = l & 15, lq = l >> 4;
    f32x4 acc[8];
    {
        int ob = w * 16 + lq * 4;      // D row = (l>>4)*4+g  [m89-verified]
        f32x4 ini;
        ini[0] = wb[ob]; ini[1] = wb[ob + 1]; ini[2] = wb[ob + 2]; ini[3] = wb[ob + 3];
#pragma unroll
        for (int xt = 0; xt < 8; ++xt) acc[xt] = ini;
    }
    for (int ph = 0; ph < 3; ++ph) {
        // ---- stage H-side: 32 k-rows x 128 x (h channels, or trig modes at ph2)
        {
            const float* src; size_t str;
            if (ph < 2) {
                src = h + (size_t)(b * 64 + ph * 32 + half * 16) * HW + y * 256 + x0 + xs;
                str = HW;
            } else {
                src = trig + (half * 16) * 256 + x0 + xs;
                str = 256;
            }
            float v[16];
#pragma unroll
            for (int kk = 0; kk < 16; ++kk) v[kk] = src[(size_t)kk * str];
#pragma unroll
            for (int c2 = 0; c2 < 2; ++c2) {
                uint4 hq4, lq4;
                split_pack8(v + c2 * 8, hq4, lq4);
                int cell = (half * 2 + c2) * 128 + xs;
                sHh[cell] = hq4; sHl[cell] = lq4;
            }
        }
        // ---- stage W-side: 32 k-rows x 64 o (wwT channels, or Gq modes at ph2)
        {
            const float* src = (ph < 2)
                ? (wwT + (ph * 32 + q * 8) * 64 + os)
                : (Gq + ((size_t)(b * 256 + y) * 32 + q * 8) * 64 + os);
            float v[8];
#pragma unroll
            for (int kk = 0; kk < 8; ++kk) v[kk] = src[kk * 64];
            uint4 hq4, lq4;
            split_pack8(v, hq4, lq4);
            int cell = q * 64 + os;
            sWh[cell] = hq4; sWl[cell] = lq4;
        }
        __syncthreads();
        // A frag: lane holds W[o = w*16 + (l&15)][k = (l>>4)*8 + j]
        bf16x8 Ah = __builtin_bit_cast(bf16x8, sWh[lq * 64 + w * 16 + lr]);
        bf16x8 Al = __builtin_bit_cast(bf16x8, sWl[lq * 64 + w * 16 + lr]);
#pragma unroll
        for (int xt = 0; xt < 8; ++xt) {
            // B frag: lane holds H[k = (l>>4)*8 + j][x = xt*16 + (l&15)]
            bf16x8 Bh = __builtin_bit_cast(bf16x8, sHh[lq * 128 + xt * 16 + lr]);
            bf16x8 Bl = __builtin_bit_cast(bf16x8, sHl[lq * 128 + xt * 16 + lr]);
            acc[xt] = __builtin_amdgcn_mfma_f32_16x16x32_bf16(Ah, Bh, acc[xt], 0, 0, 0);
            acc[xt] = __builtin_amdgcn_mfma_f32_16x16x32_bf16(Ah, Bl, acc[xt], 0, 0, 0);
            acc[xt] = __builtin_amdgcn_mfma_f32_16x16x32_bf16(Al, Bh, acc[xt], 0, 0, 0);
        }
        __syncthreads();
    }
    // epilogue: relu + store (16-lane x 64B segments per o-row)
#pragma unroll
    for (int g = 0; g < 4; ++g) {
        int o = w * 16 + lq * 4 + g;
        float* dst = h + (size_t)(b * 64 + o) * HW + y * 256 + x0 + lr;
#pragma unroll
        for (int xt = 0; xt < 8; ++xt)
            dst[xt * 16] = fmaxf(acc[xt][g], 0.f);
    }
}

// ---------------- fc1+fc2: split-bf16 MFMA GEMM + in-reg fc2 reduce ----------------
// R14: same conversion. 128m x 128x tile, K=64 in 2 phases. Wave w owns m-rows
// [w*32, w*32+32). fc2 done from D-fragments in registers: shfl_xor(16/32)
// reduce over the 4 lane-quadrants, LDS partial over 4 waves. 32 KB LDS.
__global__ __launch_bounds__(256, 3)
void k_fc12(const float* __restrict__ h, const float* __restrict__ w1T,
            const float* __restrict__ b1, const float* __restrict__ w2,
            const float* __restrict__ b2, float* __restrict__ out) {
    __shared__ uint4 sHh[512], sHl[512];   // [kc(4)][x(128)] 16 KB
    __shared__ uint4 sWh[512], sWl[512];   // [kc(4)][m(128)] 16 KB
    int blk = blockIdx.x;                  // b(8) * y(256) * xq(2), xq fastest
    int xq = blk & 1, y = (blk >> 1) & 255, b = blk >> 9;
    int x0 = xq * 128;
    int t = threadIdx.x;
    int xs = t & 127, half = t >> 7;
    int w = t >> 6, l = t & 63;
    int lr = l & 15, lq = l >> 4;
    int mb = w * 32;
    f32x4 acc[2][8];
#pragma unroll
    for (int u = 0; u < 2; ++u) {
        int m0 = mb + u * 16 + lq * 4;
        f32x4 ini;
        ini[0] = b1[m0]; ini[1] = b1[m0 + 1]; ini[2] = b1[m0 + 2]; ini[3] = b1[m0 + 3];
#pragma unroll
        for (int xt = 0; xt < 8; ++xt) acc[u][xt] = ini;
    }
    for (int ph = 0; ph < 2; ++ph) {
        {   // H: 32 c-rows x 128 x
            const float* src = h + (size_t)(b * 64 + ph * 32 + half * 16) * HW + y * 256 + x0 + xs;
            float v[16];
#pragma unroll
            for (int kk = 0; kk < 16; ++kk) v[kk] = src[(size_t)kk * HW];
#pragma unroll
            for (int c2 = 0; c2 < 2; ++c2) {
                uint4 hq4, lq4;
                split_pack8(v + c2 * 8, hq4, lq4);
                int cell = (half * 2 + c2) * 128 + xs;
                sHh[cell] = hq4; sHl[cell] = lq4;
            }
        }
        {   // W1: 32 c-rows x 128 m   (w1T[i][m], stride 128 over i)
            const float* src = w1T + (ph * 32 + half * 16) * 128 + xs;
            float v[16];
#pragma unroll
            for (int kk = 0; kk < 16; ++kk) v[kk] = src[kk * 128];
#pragma unroll
            for (int c2 = 0; c2 < 2; ++c2) {
                uint4 hq4, lq4;
                split_pack8(v + c2 * 8, hq4, lq4);
                int cell = (half * 2 + c2) * 128 + xs;
                sWh[cell] = hq4; sWl[cell] = lq4;
            }
        }
        __syncthreads();
        bf16x8 Ah[2], Al[2];
#pragma unroll
        for (int u = 0; u < 2; ++u) {
            Ah[u] = __builtin_bit_cast(bf16x8, sWh[lq * 128 + mb + u * 16 + lr]);
            Al[u] = __builtin_bit_cast(bf16x8, sWl[lq * 128 + mb + u * 16 + lr]);
        }
#pragma unroll
        for (int xt = 0; xt < 8; ++xt) {
            bf16x8 Bh = __builtin_bit_cast(bf16x8, sHh[lq * 128 + xt * 16 + lr]);
            bf16x8 Bl = __builtin_bit_cast(bf16x8, sHl[lq * 128 + xt * 16 + lr]);
#pragma unroll
            for (int u = 0; u < 2; ++u) {
                acc[u][xt] = __builtin_amdgcn_mfma_f32_16x16x32_bf16(Ah[u], Bh, acc[u][xt], 0, 0, 0);
                acc[u][xt] = __builtin_amdgcn_mfma_f32_16x16x32_bf16(Ah[u], Bl, acc[u][xt], 0, 0, 0);
                acc[u][xt] = __builtin_amdgcn_mfma_f32_16x16x32_bf16(Al[u], Bh, acc[u][xt], 0, 0, 0);
            }
        }
        __syncthreads();
    }
    // relu + fc2 partials: lane holds D[m = mb+u*16+lq*4+g][x = xt*16+lr]
    float pj[3][8];
#pragma unroll
    for (int j = 0; j < 3; ++j)
#pragma unroll
        for (int xt = 0; xt < 8; ++xt) pj[j][xt] = 0.f;
#pragma unroll
    for (int u = 0; u < 2; ++u)
#pragma unroll
        for (int g = 0; g < 4; ++g) {
            int m = mb + u * 16 + lq * 4 + g;
            float w20 = w2[m], w21 = w2[NMLP + m], w22 = w2[2 * NMLP + m];
#pragma unroll
            for (int xt = 0; xt < 8; ++xt) {
                float r = fmaxf(acc[u][xt][g], 0.f);
                pj[0][xt] = fmaf(w20, r, pj[0][xt]);
                pj[1][xt] = fmaf(w21, r, pj[1][xt]);
                pj[2][xt] = fmaf(w22, r, pj[2][xt]);
            }
        }
    // reduce lane-quadrants (m-subrows) via shfl, then the 4 waves via LDS
#pragma unroll
    for (int j = 0; j < 3; ++j)
#pragma unroll
        for (int xt = 0; xt < 8; ++xt) {
            float v = pj[j][xt];
            v += __shfl_xor(v, 16);
            v += __shfl_xor(v, 32);
            pj[j][xt] = v;
        }
    float* part = (float*)sHh;   // 4*3*128 floats = 6 KB; all MFMA LDS reads done
    if (lq == 0) {
#pragma unroll
        for (int j = 0; j < 3; ++j)
#pragma unroll
            for (int xt = 0; xt < 8; ++xt)
                part[(w * 3 + j) * 128 + xt * 16 + lr] = pj[j][xt];
    }
    __syncthreads();
#pragma unroll
    for (int r = 0; r < 2; ++r) {
        int idx = t + r * 256;
        if (idx < 384) {
            int j = idx >> 7, xx = idx & 127;
            float s = b2[j];
#pragma unroll
            for (int ww2 = 0; ww2 < 4; ++ww2) s += part[(ww2 * 3 + j) * 128 + xx];
            out[(size_t)(b * 3 + j) * HW + y * 256 + x0 + xx] = s;
        }
    }
}

extern "C" void kernel_launch(void* const* d_in, const int* in_sizes, int n_in,
                              void* d_out, int out_size, void* d_ws, size_t ws_size,
                              hipStream_t stream) {
    const float* x     = (const float*)d_in[0];
    const float* fc0_w = (const float*)d_in[1];
    const float* fc0_b = (const float*)d_in[2];
    const float* swre  = (const float*)d_in[3];
    const float* swim  = (const float*)d_in[4];
    const float* ww    = (const float*)d_in[5];
    const float* wb    = (const float*)d_in[6];
    const float* fc1w  = (const float*)d_in[7];
    const float* fc1b  = (const float*)d_in[8];
    const float* fc2w  = (const float*)d_in[9];
    const float* fc2b  = (const float*)d_in[10];

    float* ws = (float*)d_ws;
    float2* tab    = (float2*)ws;                     // 512 floats
    float*  h      = ws + 512;                        // 33,554,432
    float*  T1F    = ws + 33554944;                   // 4,194,304
    float2* X      = (float2*)(ws + 37749248);        // 262,144 floats
    float2* Y      = (float2*)(ws + 38011392);        // 262,144 floats
    float*  Gq     = ws + 38273536;                   // 4,194,304
    float*  wwT    = ws + 42467840;                   // 16,384
    float*  w1T    = ws + 42484224;                   // 8,192
    float*  trig   = ws + 42492416;                   // 8,192
    float*  trigFT = ws + 42500608;                   // 8,192

    k_table<<<dim3(1), dim3(256), 0, stream>>>(tab);
    k_prep0<<<dim3(160), dim3(256), 0, stream>>>(tab, fc1w, ww, trig, trigFT, w1T, wwT);
    k_fc0<<<dim3(2048), dim3(256), 0, stream>>>(x, fc0_w, fc0_b, h);

    for (int d = 0; d < NDEPTH; ++d) {
        k_fwd_y<<<dim3(512), dim3(128), 0, stream>>>(h, trigFT, T1F);
        k_fwd_x<<<dim3(512), dim3(256), 0, stream>>>(T1F, trig, X);
        k_mix<<<dim3(256), dim3(256), 0, stream>>>(X, swre + (size_t)d * C * C * 256,
                                                   swim + (size_t)d * C * C * 256, Y);
        k_invy<<<dim3(512), dim3(256), 0, stream>>>(Y, tab, Gq);
        k_final<<<dim3(4096), dim3(256), 0, stream>>>(h, Gq, wwT + d * 4096, wb + d * C, trig);
    }
    k_fc12<<<dim3(4096), dim3(256), 0, stream>>>(h, w1T, fc1b, fc2w, fc2b, (float*)d_out);
}

// Round 2
// 630.452 us; speedup vs baseline: 1.5040x; 1.1208x over previous
//
#include <hip/hip_runtime.h>

#define Hd 256
#define Wd 256
#define HW 65536
#define C 64
#define B 8
#define M 16
#define NDEPTH 4
#define NMLP 128

typedef __attribute__((ext_vector_type(8))) __bf16 bf16x8;
typedef __attribute__((ext_vector_type(4))) float f32x4;

// split fp32 -> bf16 hi (RNE) + bf16 lo (RNE of residual); pack 8 values into
// one uint4 per plane (k-contiguous 16B cell for ds_read_b128 MFMA fragments).
__device__ inline void split_pack8(const float* v, uint4& hq, uint4& lq) {
    unsigned hw[4], lw[4];
#pragma unroll
    for (int i = 0; i < 4; ++i) {
        float a = v[2 * i], bb = v[2 * i + 1];
        unsigned ua = __float_as_uint(a);
        unsigned ha = (ua + 0x7fffu + ((ua >> 16) & 1u)) & 0xffff0000u;
        float ra = a - __uint_as_float(ha);
        unsigned ural = __float_as_uint(ra);
        unsigned la = (ural + 0x7fffu + ((ural >> 16) & 1u)) >> 16;
        unsigned ub = __float_as_uint(bb);
        unsigned hb = (ub + 0x7fffu + ((ub >> 16) & 1u)) & 0xffff0000u;
        float rb = bb - __uint_as_float(hb);
        unsigned urbl = __float_as_uint(rb);
        unsigned lb = (urbl + 0x7fffu + ((urbl >> 16) & 1u)) >> 16;
        hw[i] = (ha >> 16) | (hb & 0xffff0000u);
        lw[i] = la | (lb << 16);
    }
    hq = make_uint4(hw[0], hw[1], hw[2], hw[3]);
    lq = make_uint4(lw[0], lw[1], lw[2], lw[3]);
}

// ---------------- twiddle table ----------------
__global__ void k_table(float2* __restrict__ tab) {
    int t = threadIdx.x;
    double a = (6.283185307179586476925286766559 / 256.0) * (double)t;
    tab[t] = make_float2((float)cos(a), (float)sin(a));
}

// ---------------- once: trig, trigFT, w1T, wwT_all ----------------
__global__ void k_prep0(const float2* __restrict__ tab, const float* __restrict__ fc1w,
                        const float* __restrict__ ww,
                        float* __restrict__ trig, float* __restrict__ trigFT,
                        float* __restrict__ w1T, float* __restrict__ wwT_all) {
    int blk = blockIdx.x, t = threadIdx.x;
    if (blk < 32) {                    // trig[kk][x]: cos kk<16, +sin kk>=16
        int k = blk & 15;
        float2 e = tab[(k * t) & 255];
        trig[blk * 256 + t] = (blk < 16) ? e.x : e.y;
    } else if (blk < 64) {             // trigFT[y][kk]: cos kk<16, -sin kk>=16
        int f = (blk - 32) * 256 + t;
        int y = f >> 5, kk = f & 31;
        float2 e = tab[((kk & 15) * y) & 255];
        trigFT[f] = (kk < 16) ? e.x : -e.y;
    } else if (blk < 96) {             // w1T[i][m] = fc1w[m][i]
        int f = (blk - 64) * 256 + t;
        int i = f >> 7, m = f & 127;
        w1T[f] = fc1w[m * 64 + i];
    } else {                           // wwT_all[d][i][o] = ww[d][o][i]
        int f = (blk - 96) * 256 + t;
        int d = f >> 12, r = f & 4095;
        int i = r >> 6, o = r & 63;
        wwT_all[f] = ww[d * 4096 + o * 64 + i];
    }
}

// ---------------- once: split-bf16 A-fragments of the y-DFT matrix ----------------
// ET cell c = ph*128 + kc*32 + m  holds trigFT-equivalent values for
// k = y = ph*32 + kc*8 + j (j = element 0..7), row m (cos m<16, -sin m>=16).
// Exactly matches the MFMA A-fragment load: lane(lr,lq) reads cell ph*128+lq*32+m.
__global__ void k_prep_et(const float2* __restrict__ tab,
                          uint4* __restrict__ ETh, uint4* __restrict__ ETl) {
    int c = blockIdx.x * 256 + threadIdx.x;
    if (c >= 1024) return;
    int ph = c >> 7, kc = (c >> 5) & 3, m = c & 31;
    float v[8];
#pragma unroll
    for (int j = 0; j < 8; ++j) {
        int y = ph * 32 + kc * 8 + j;
        float2 e = tab[((m & 15) * y) & 255];
        v[j] = (m < 16) ? e.x : -e.y;
    }
    uint4 hq, lq;
    split_pack8(v, hq, lq);
    ETh[c] = hq; ETl[c] = lq;
}

// ---------------- fc0 ----------------
__global__ void k_fc0(const float* __restrict__ x, const float* __restrict__ w,
                      const float* __restrict__ bias, float* __restrict__ h) {
    int p = blockIdx.x * 256 + threadIdx.x;
    int b = p >> 16, pix = p & 65535;
    float x0 = x[(b * 3 + 0) * HW + pix];
    float x1 = x[(b * 3 + 1) * HW + pix];
    float x2 = x[(b * 3 + 2) * HW + pix];
    for (int o = 0; o < C; ++o) {
        float v = bias[o];
        v = fmaf(w[o * 3 + 0], x0, v);
        v = fmaf(w[o * 3 + 1], x1, v);
        v = fmaf(w[o * 3 + 2], x2, v);
        h[(b * C + o) * HW + pix] = v;
    }
}

// ---------------- forward y-DFT: split-bf16 MFMA GEMM ----------------
// R15: was fp32 VALU GEMM (~2.75 GFLOP/dispatch + full 134 MB h read). Now
// M=32 (modes), N=128 (x-half), K=256 (y) per block, 8 K-phases of 32.
// A-fragments come pre-split/pre-transposed from ET (global, L2-hot).
// B staged via split_pack8 into [kc][x][8k] cells -> conflict-free ds_read_b128.
__global__ __launch_bounds__(256, 4)
void k_fwd_y(const float* __restrict__ h, const uint4* __restrict__ ETh,
             const uint4* __restrict__ ETl, float* __restrict__ T1F) {
    __shared__ uint4 sBh[512], sBl[512];   // [kc(4)][x(128)] 8 KB each
    int blk = blockIdx.x;                  // bc(512) * xh(2), xh fastest
    int xh = blk & 1, bc = blk >> 1;
    int x0 = xh * 128;
    int t = threadIdx.x;
    int xs = t & 127, half = t >> 7;       // staging: x=xs, k-run half*16..+15
    int w = t >> 6, l = t & 63;            // wave w owns x in [w*32, w*32+32)
    int lr = l & 15, lq = l >> 4;
    f32x4 acc[2][2];
#pragma unroll
    for (int u = 0; u < 2; ++u)
#pragma unroll
        for (int xt = 0; xt < 2; ++xt) {
            acc[u][xt][0] = 0.f; acc[u][xt][1] = 0.f;
            acc[u][xt][2] = 0.f; acc[u][xt][3] = 0.f;
        }
    for (int ph = 0; ph < 8; ++ph) {
        {   // stage B: y-rows ph*32 + half*16 .. +15, x = x0 + xs
            const float* src = h + (size_t)bc * HW + (ph * 32 + half * 16) * 256 + x0 + xs;
            float v[16];
#pragma unroll
            for (int kk = 0; kk < 16; ++kk) v[kk] = src[kk * 256];
#pragma unroll
            for (int c2 = 0; c2 < 2; ++c2) {
                uint4 hq4, lq4;
                split_pack8(v + c2 * 8, hq4, lq4);
                int cell = (half * 2 + c2) * 128 + xs;
                sBh[cell] = hq4; sBl[cell] = lq4;
            }
        }
        __syncthreads();
        bf16x8 Ah[2], Al[2];
#pragma unroll
        for (int u = 0; u < 2; ++u) {
            int ci = ph * 128 + lq * 32 + u * 16 + lr;
            Ah[u] = __builtin_bit_cast(bf16x8, ETh[ci]);
            Al[u] = __builtin_bit_cast(bf16x8, ETl[ci]);
        }
#pragma unroll
        for (int xt = 0; xt < 2; ++xt) {
            bf16x8 Bh = __builtin_bit_cast(bf16x8, sBh[lq * 128 + w * 32 + xt * 16 + lr]);
            bf16x8 Bl = __builtin_bit_cast(bf16x8, sBl[lq * 128 + w * 32 + xt * 16 + lr]);
#pragma unroll
            for (int u = 0; u < 2; ++u) {
                acc[u][xt] = __builtin_amdgcn_mfma_f32_16x16x32_bf16(Ah[u], Bh, acc[u][xt], 0, 0, 0);
                acc[u][xt] = __builtin_amdgcn_mfma_f32_16x16x32_bf16(Ah[u], Bl, acc[u][xt], 0, 0, 0);
                acc[u][xt] = __builtin_amdgcn_mfma_f32_16x16x32_bf16(Al[u], Bh, acc[u][xt], 0, 0, 0);
            }
        }
        __syncthreads();
    }
    // D: row = u*16 + lq*4 + g (mode kk), col = x0 + w*32 + xt*16 + lr
#pragma unroll
    for (int u = 0; u < 2; ++u)
#pragma unroll
        for (int xt = 0; xt < 2; ++xt)
#pragma unroll
            for (int g = 0; g < 4; ++g)
                T1F[(size_t)bc * 8192 + (u * 16 + lq * 4 + g) * 256 + x0 + w * 32 + xt * 16 + lr] =
                    acc[u][xt][g];
}

// ---------------- forward x-DFT (unchanged from R12) ----------------
__global__ __launch_bounds__(256, 2)
void k_fwd_x(const float* __restrict__ T1F, const float* __restrict__ trig,
             float2* __restrict__ X) {
    __shared__ float sT[32 * 260];
    __shared__ float sG[32 * 260];
    int bc = blockIdx.x, t = threadIdx.x;
#pragma unroll
    for (int p = 0; p < 8; ++p) {
        int f = t + p * 256;
        int row = f >> 6, seg = f & 63;
        ((float4*)(sT + row * 260))[seg] = *(const float4*)(T1F + (size_t)bc * 8192 + f * 4);
        ((float4*)(sG + row * 260))[seg] = *(const float4*)(trig + row * 256 + seg * 4);
    }
    __syncthreads();
    int ky = t >> 4, kx = t & 15;
    const float* Tr = sT + ky * 260;
    const float* Ti = sT + (16 + ky) * 260;
    const float* Cs = sG + kx * 260;
    const float* Sn = sG + (16 + kx) * 260;
    float xr0 = 0.f, xi0 = 0.f, xr1 = 0.f, xi1 = 0.f;
    for (int q = 0; q < 64; q += 2) {
        float4 tr = *(const float4*)(Tr + q * 4);
        float4 ti = *(const float4*)(Ti + q * 4);
        float4 cs = *(const float4*)(Cs + q * 4);
        float4 sn = *(const float4*)(Sn + q * 4);
        xr0 = fmaf(tr.x, cs.x, xr0); xr0 = fmaf(ti.x, sn.x, xr0);
        xi0 = fmaf(ti.x, cs.x, xi0); xi0 = fmaf(-tr.x, sn.x, xi0);
        xr0 = fmaf(tr.y, cs.y, xr0); xr0 = fmaf(ti.y, sn.y, xr0);
        xi0 = fmaf(ti.y, cs.y, xi0); xi0 = fmaf(-tr.y, sn.y, xi0);
        xr0 = fmaf(tr.z, cs.z, xr0); xr0 = fmaf(ti.z, sn.z, xr0);
        xi0 = fmaf(ti.z, cs.z, xi0); xi0 = fmaf(-tr.z, sn.z, xi0);
        xr0 = fmaf(tr.w, cs.w, xr0); xr0 = fmaf(ti.w, sn.w, xr0);
        xi0 = fmaf(ti.w, cs.w, xi0); xi0 = fmaf(-tr.w, sn.w, xi0);
        float4 tr1 = *(const float4*)(Tr + q * 4 + 4);
        float4 ti1 = *(const float4*)(Ti + q * 4 + 4);
        float4 cs1 = *(const float4*)(Cs + q * 4 + 4);
        float4 sn1 = *(const float4*)(Sn + q * 4 + 4);
        xr1 = fmaf(tr1.x, cs1.x, xr1); xr1 = fmaf(ti1.x, sn1.x, xr1);
        xi1 = fmaf(ti1.x, cs1.x, xi1); xi1 = fmaf(-tr1.x, sn1.x, xi1);
        xr1 = fmaf(tr1.y, cs1.y, xr1); xr1 = fmaf(ti1.y, sn1.y, xr1);
        xi1 = fmaf(ti1.y, cs1.y, xi1); xi1 = fmaf(-tr1.y, sn1.y, xi1);
        xr1 = fmaf(tr1.z, cs1.z, xr1); xr1 = fmaf(ti1.z, sn1.z, xr1);
        xi1 = fmaf(ti1.z, cs1.z, xi1); xi1 = fmaf(-tr1.z, sn1.z, xi1);
        xr1 = fmaf(tr1.w, cs1.w, xr1); xr1 = fmaf(ti1.w, sn1.w, xr1);
        xi1 = fmaf(ti1.w, cs1.w, xi1); xi1 = fmaf(-tr1.w, sn1.w, xi1);
    }
    X[bc * 256 + t] = make_float2(xr0 + xr1, xi0 + xi1);
}

// ---------------- mode mixing (unchanged) ----------------
__global__ __launch_bounds__(256, 2)
void k_mix(const float2* __restrict__ X, const float* __restrict__ wre,
           const float* __restrict__ wim, float2* __restrict__ Y) {
    int o = blockIdx.x >> 2;
    int bq = blockIdx.x & 3;
    int m = threadIdx.x;
    int b0 = bq * 2, b1 = bq * 2 + 1;
    float yr0 = 0.f, yi0 = 0.f, yr1 = 0.f, yi1 = 0.f;
    for (int i = 0; i < C; ++i) {
        float wr = wre[(i * C + o) * 256 + m];
        float wi = wim[(i * C + o) * 256 + m];
        float2 x0 = X[(b0 * C + i) * 256 + m];
        float2 x1 = X[(b1 * C + i) * 256 + m];
        yr0 = fmaf(x0.x, wr, fmaf(-x0.y, wi, yr0));
        yi0 = fmaf(x0.x, wi, fmaf(x0.y, wr, yi0));
        yr1 = fmaf(x1.x, wr, fmaf(-x1.y, wi, yr1));
        yi1 = fmaf(x1.x, wi, fmaf(x1.y, wr, yi1));
    }
    Y[(b0 * C + o) * 256 + m] = make_float2(yr0, yi0);
    Y[(b1 * C + o) * 256 + m] = make_float2(yr1, yi1);
}

// ---------------- fused inverse-y + Gq production (unchanged) ----------------
__global__ __launch_bounds__(256, 2)
void k_invy(const float2* __restrict__ Y, const float2* __restrict__ tab,
            float* __restrict__ Gq) {
    __shared__ float2 st[256];
    int blk = blockIdx.x;              // 8b x 4pg x 16yt
    int yt = blk & 15, pg = (blk >> 4) & 3, b = blk >> 6;
    int t = threadIdx.x;
    st[t] = tab[t];
    int o = t & 63, kx = pg * 4 + (t >> 6);
    __syncthreads();
    float sc = (kx == 0 ? 1.0f : 2.0f) * (1.0f / 65536.0f);
    float yr[16], yi[16];
    const float2* yp = Y + (size_t)(b * 64 + o) * 256 + kx;
#pragma unroll
    for (int ky = 0; ky < 16; ++ky) {
        float2 v = yp[ky * 16];
        yr[ky] = v.x * sc;
        yi[ky] = v.y * sc;
    }
    int y0 = yt * 16;
    for (int yy = 0; yy < 16; ++yy) {
        int y = y0 + yy;
        float re = 0.f, im = 0.f;
#pragma unroll
        for (int ky = 0; ky < 16; ++ky) {
            float2 e = st[(ky * y) & 255];
            re = fmaf(yr[ky], e.x, re);
            re = fmaf(-yi[ky], e.y, re);
            im = fmaf(yr[ky], e.y, im);
            im = fmaf(yi[ky], e.x, im);
        }
        float* gp = Gq + (size_t)(b * 256 + y) * 32 * 64 + o;
        gp[kx * 64] = re;
        gp[(16 + kx) * 64] = -im;
    }
}

// ---------------- k_final: split-bf16 MFMA augmented GEMM ----------------
__global__ __launch_bounds__(256, 4)
void k_final(float* __restrict__ h, const float* __restrict__ Gq,
             const float* __restrict__ wwT, const float* __restrict__ wb,
             const float* __restrict__ trig) {
    __shared__ uint4 sHh[512], sHl[512];   // [kc(4)][x(128)] 16 KB
    __shared__ uint4 sWh[256], sWl[256];   // [kc(4)][o(64)]   8 KB
    int blk = blockIdx.x;              // b(8) * y(256) * xq(2), xq fastest
    int xq = blk & 1, y = (blk >> 1) & 255, b = blk >> 9;
    int x0 = xq * 128;
    int t = threadIdx.x;
    int xs = t & 127, half = t >> 7;   // H staging: thread owns x=xs, k-run half*16..+15
    int os = t & 63, q = t >> 6;       // W staging: thread owns o=os, k-run q*8..+7
    int w = t >> 6, l = t & 63;        // wave w owns o-rows [w*16, w*16+16)
    int lr = l & 15, lq = l >> 4;
    f32x4 acc[8];
    {
        int ob = w * 16 + lq * 4;      // D row = (l>>4)*4+g  [m89-verified]
        f32x4 ini;
        ini[0] = wb[ob]; ini[1] = wb[ob + 1]; ini[2] = wb[ob + 2]; ini[3] = wb[ob + 3];
#pragma unroll
        for (int xt = 0; xt < 8; ++xt) acc[xt] = ini;
    }
    for (int ph = 0; ph < 3; ++ph) {
        // ---- stage H-side: 32 k-rows x 128 x (h channels, or trig modes at ph2)
        {
            const float* src; size_t str;
            if (ph < 2) {
                src = h + (size_t)(b * 64 + ph * 32 + half * 16) * HW + y * 256 + x0 + xs;
                str = HW;
            } else {
                src = trig + (half * 16) * 256 + x0 + xs;
                str = 256;
            }
            float v[16];
#pragma unroll
            for (int kk = 0; kk < 16; ++kk) v[kk] = src[(size_t)kk * str];
#pragma unroll
            for (int c2 = 0; c2 < 2; ++c2) {
                uint4 hq4, lq4;
                split_pack8(v + c2 * 8, hq4, lq4);
                int cell = (half * 2 + c2) * 128 + xs;
                sHh[cell] = hq4; sHl[cell] = lq4;
            }
        }
        // ---- stage W-side: 32 k-rows x 64 o (wwT channels, or Gq modes at ph2)
        {
            const float* src = (ph < 2)
                ? (wwT + (ph * 32 + q * 8) * 64 + os)
                : (Gq + ((size_t)(b * 256 + y) * 32 + q * 8) * 64 + os);
            float v[8];
#pragma unroll
            for (int kk = 0; kk < 8; ++kk) v[kk] = src[kk * 64];
            uint4 hq4, lq4;
            split_pack8(v, hq4, lq4);
            int cell = q * 64 + os;
            sWh[cell] = hq4; sWl[cell] = lq4;
        }
        __syncthreads();
        // A frag: lane holds W[o = w*16 + (l&15)][k = (l>>4)*8 + j]
        bf16x8 Ah = __builtin_bit_cast(bf16x8, sWh[lq * 64 + w * 16 + lr]);
        bf16x8 Al = __builtin_bit_cast(bf16x8, sWl[lq * 64 + w * 16 + lr]);
#pragma unroll
        for (int xt = 0; xt < 8; ++xt) {
            // B frag: lane holds H[k = (l>>4)*8 + j][x = xt*16 + (l&15)]
            bf16x8 Bh = __builtin_bit_cast(bf16x8, sHh[lq * 128 + xt * 16 + lr]);
            bf16x8 Bl = __builtin_bit_cast(bf16x8, sHl[lq * 128 + xt * 16 + lr]);
            acc[xt] = __builtin_amdgcn_mfma_f32_16x16x32_bf16(Ah, Bh, acc[xt], 0, 0, 0);
            acc[xt] = __builtin_amdgcn_mfma_f32_16x16x32_bf16(Ah, Bl, acc[xt], 0, 0, 0);
            acc[xt] = __builtin_amdgcn_mfma_f32_16x16x32_bf16(Al, Bh, acc[xt], 0, 0, 0);
        }
        __syncthreads();
    }
    // epilogue: relu + store (16-lane x 64B segments per o-row)
#pragma unroll
    for (int g = 0; g < 4; ++g) {
        int o = w * 16 + lq * 4 + g;
        float* dst = h + (size_t)(b * 64 + o) * HW + y * 256 + x0 + lr;
#pragma unroll
        for (int xt = 0; xt < 8; ++xt)
            dst[xt * 16] = fmaxf(acc[xt][g], 0.f);
    }
}

// ---------------- fc1+fc2: split-bf16 MFMA GEMM + in-reg fc2 reduce ----------------
__global__ __launch_bounds__(256, 3)
void k_fc12(const float* __restrict__ h, const float* __restrict__ w1T,
            const float* __restrict__ b1, const float* __restrict__ w2,
            const float* __restrict__ b2, float* __restrict__ out) {
    __shared__ uint4 sHh[512], sHl[512];   // [kc(4)][x(128)] 16 KB
    __shared__ uint4 sWh[512], sWl[512];   // [kc(4)][m(128)] 16 KB
    int blk = blockIdx.x;                  // b(8) * y(256) * xq(2), xq fastest
    int xq = blk & 1, y = (blk >> 1) & 255, b = blk >> 9;
    int x0 = xq * 128;
    int t = threadIdx.x;
    int xs = t & 127, half = t >> 7;
    int w = t >> 6, l = t & 63;
    int lr = l & 15, lq = l >> 4;
    int mb = w * 32;
    f32x4 acc[2][8];
#pragma unroll
    for (int u = 0; u < 2; ++u) {
        int m0 = mb + u * 16 + lq * 4;
        f32x4 ini;
        ini[0] = b1[m0]; ini[1] = b1[m0 + 1]; ini[2] = b1[m0 + 2]; ini[3] = b1[m0 + 3];
#pragma unroll
        for (int xt = 0; xt < 8; ++xt) acc[u][xt] = ini;
    }
    for (int ph = 0; ph < 2; ++ph) {
        {   // H: 32 c-rows x 128 x
            const float* src = h + (size_t)(b * 64 + ph * 32 + half * 16) * HW + y * 256 + x0 + xs;
            float v[16];
#pragma unroll
            for (int kk = 0; kk < 16; ++kk) v[kk] = src[(size_t)kk * HW];
#pragma unroll
            for (int c2 = 0; c2 < 2; ++c2) {
                uint4 hq4, lq4;
                split_pack8(v + c2 * 8, hq4, lq4);
                int cell = (half * 2 + c2) * 128 + xs;
                sHh[cell] = hq4; sHl[cell] = lq4;
            }
        }
        {   // W1: 32 c-rows x 128 m   (w1T[i][m], stride 128 over i)
            const float* src = w1T + (ph * 32 + half * 16) * 128 + xs;
            float v[16];
#pragma unroll
            for (int kk = 0; kk < 16; ++kk) v[kk] = src[kk * 128];
#pragma unroll
            for (int c2 = 0; c2 < 2; ++c2) {
                uint4 hq4, lq4;
                split_pack8(v + c2 * 8, hq4, lq4);
                int cell = (half * 2 + c2) * 128 + xs;
                sWh[cell] = hq4; sWl[cell] = lq4;
            }
        }
        __syncthreads();
        bf16x8 Ah[2], Al[2];
#pragma unroll
        for (int u = 0; u < 2; ++u) {
            Ah[u] = __builtin_bit_cast(bf16x8, sWh[lq * 128 + mb + u * 16 + lr]);
            Al[u] = __builtin_bit_cast(bf16x8, sWl[lq * 128 + mb + u * 16 + lr]);
        }
#pragma unroll
        for (int xt = 0; xt < 8; ++xt) {
            bf16x8 Bh = __builtin_bit_cast(bf16x8, sHh[lq * 128 + xt * 16 + lr]);
            bf16x8 Bl = __builtin_bit_cast(bf16x8, sHl[lq * 128 + xt * 16 + lr]);
#pragma unroll
            for (int u = 0; u < 2; ++u) {
                acc[u][xt] = __builtin_amdgcn_mfma_f32_16x16x32_bf16(Ah[u], Bh, acc[u][xt], 0, 0, 0);
                acc[u][xt] = __builtin_amdgcn_mfma_f32_16x16x32_bf16(Ah[u], Bl, acc[u][xt], 0, 0, 0);
                acc[u][xt] = __builtin_amdgcn_mfma_f32_16x16x32_bf16(Al[u], Bh, acc[u][xt], 0, 0, 0);
            }
        }
        __syncthreads();
    }
    // relu + fc2 partials: lane holds D[m = mb+u*16+lq*4+g][x = xt*16+lr]
    float pj[3][8];
#pragma unroll
    for (int j = 0; j < 3; ++j)
#pragma unroll
        for (int xt = 0; xt < 8; ++xt) pj[j][xt] = 0.f;
#pragma unroll
    for (int u = 0; u < 2; ++u)
#pragma unroll
        for (int g = 0; g < 4; ++g) {
            int m = mb + u * 16 + lq * 4 + g;
            float w20 = w2[m], w21 = w2[NMLP + m], w22 = w2[2 * NMLP + m];
#pragma unroll
            for (int xt = 0; xt < 8; ++xt) {
                float r = fmaxf(acc[u][xt][g], 0.f);
                pj[0][xt] = fmaf(w20, r, pj[0][xt]);
                pj[1][xt] = fmaf(w21, r, pj[1][xt]);
                pj[2][xt] = fmaf(w22, r, pj[2][xt]);
            }
        }
    // reduce lane-quadrants (m-subrows) via shfl, then the 4 waves via LDS
#pragma unroll
    for (int j = 0; j < 3; ++j)
#pragma unroll
        for (int xt = 0; xt < 8; ++xt) {
            float v = pj[j][xt];
            v += __shfl_xor(v, 16);
            v += __shfl_xor(v, 32);
            pj[j][xt] = v;
        }
    float* part = (float*)sHh;   // 4*3*128 floats = 6 KB; all GEMM LDS reads done
    if (lq == 0) {
#pragma unroll
        for (int j = 0; j < 3; ++j)
#pragma unroll
            for (int xt = 0; xt < 8; ++xt)
                part[(w * 3 + j) * 128 + xt * 16 + lr] = pj[j][xt];
    }
    __syncthreads();
#pragma unroll
    for (int r = 0; r < 2; ++r) {
        int idx = t + r * 256;
        if (idx < 384) {
            int j = idx >> 7, xx = idx & 127;
            float s = b2[j];
#pragma unroll
            for (int ww2 = 0; ww2 < 4; ++ww2) s += part[(ww2 * 3 + j) * 128 + xx];
            out[(size_t)(b * 3 + j) * HW + y * 256 + x0 + xx] = s;
        }
    }
}

extern "C" void kernel_launch(void* const* d_in, const int* in_sizes, int n_in,
                              void* d_out, int out_size, void* d_ws, size_t ws_size,
                              hipStream_t stream) {
    const float* x     = (const float*)d_in[0];
    const float* fc0_w = (const float*)d_in[1];
    const float* fc0_b = (const float*)d_in[2];
    const float* swre  = (const float*)d_in[3];
    const float* swim  = (const float*)d_in[4];
    const float* ww    = (const float*)d_in[5];
    const float* wb    = (const float*)d_in[6];
    const float* fc1w  = (const float*)d_in[7];
    const float* fc1b  = (const float*)d_in[8];
    const float* fc2w  = (const float*)d_in[9];
    const float* fc2b  = (const float*)d_in[10];

    float* ws = (float*)d_ws;
    float2* tab    = (float2*)ws;                     // 512 floats
    float*  h      = ws + 512;                        // 33,554,432
    float*  T1F    = ws + 33554944;                   // 4,194,304
    float2* X      = (float2*)(ws + 37749248);        // 262,144 floats
    float2* Y      = (float2*)(ws + 38011392);        // 262,144 floats
    float*  Gq     = ws + 38273536;                   // 4,194,304
    float*  wwT    = ws + 42467840;                   // 16,384
    float*  w1T    = ws + 42484224;                   // 8,192
    float*  trig   = ws + 42492416;                   // 8,192
    float*  trigFT = ws + 42500608;                   // 8,192
    uint4*  ETh    = (uint4*)(ws + 42508800);         // 1024 cells = 16 KB
    uint4*  ETl    = (uint4*)(ws + 42512896);         // 1024 cells = 16 KB

    k_table<<<dim3(1), dim3(256), 0, stream>>>(tab);
    k_prep0<<<dim3(160), dim3(256), 0, stream>>>(tab, fc1w, ww, trig, trigFT, w1T, wwT);
    k_prep_et<<<dim3(4), dim3(256), 0, stream>>>(tab, ETh, ETl);
    k_fc0<<<dim3(2048), dim3(256), 0, stream>>>(x, fc0_w, fc0_b, h);

    for (int d = 0; d < NDEPTH; ++d) {
        k_fwd_y<<<dim3(1024), dim3(256), 0, stream>>>(h, ETh, ETl, T1F);
        k_fwd_x<<<dim3(512), dim3(256), 0, stream>>>(T1F, trig, X);
        k_mix<<<dim3(256), dim3(256), 0, stream>>>(X, swre + (size_t)d * C * C * 256,
                                                   swim + (size_t)d * C * C * 256, Y);
        k_invy<<<dim3(512), dim3(256), 0, stream>>>(Y, tab, Gq);
        k_final<<<dim3(4096), dim3(256), 0, stream>>>(h, Gq, wwT + d * 4096, wb + d * C, trig);
    }
    k_fc12<<<dim3(4096), dim3(256), 0, stream>>>(h, w1T, fc1b, fc2w, fc2b, (float*)d_out);
}

// Round 3
// 618.471 us; speedup vs baseline: 1.5331x; 1.0194x over previous
//
#include <hip/hip_runtime.h>

#define Hd 256
#define Wd 256
#define HW 65536
#define C 64
#define B 8
#define M 16
#define NDEPTH 4
#define NMLP 128

typedef __attribute__((ext_vector_type(8))) __bf16 bf16x8;
typedef __attribute__((ext_vector_type(4))) float f32x4;

// lgkm-only barrier: ds_write visibility without draining vmcnt (prefetch stays
// in flight). __syncthreads() would emit s_waitcnt vmcnt(0) before s_barrier.
__device__ inline void bar_lgkm() {
    asm volatile("s_waitcnt lgkmcnt(0)" ::: "memory");
    __builtin_amdgcn_s_barrier();
}

// split fp32 -> bf16 hi (RNE) + bf16 lo (RNE of residual); pack 8 values into
// one uint4 per plane (k-contiguous 16B cell for ds_read_b128 MFMA fragments).
__device__ inline void split_pack8(const float* v, uint4& hq, uint4& lq) {
    unsigned hw[4], lw[4];
#pragma unroll
    for (int i = 0; i < 4; ++i) {
        float a = v[2 * i], bb = v[2 * i + 1];
        unsigned ua = __float_as_uint(a);
        unsigned ha = (ua + 0x7fffu + ((ua >> 16) & 1u)) & 0xffff0000u;
        float ra = a - __uint_as_float(ha);
        unsigned ural = __float_as_uint(ra);
        unsigned la = (ural + 0x7fffu + ((ural >> 16) & 1u)) >> 16;
        unsigned ub = __float_as_uint(bb);
        unsigned hb = (ub + 0x7fffu + ((ub >> 16) & 1u)) & 0xffff0000u;
        float rb = bb - __uint_as_float(hb);
        unsigned urbl = __float_as_uint(rb);
        unsigned lb = (urbl + 0x7fffu + ((urbl >> 16) & 1u)) >> 16;
        hw[i] = (ha >> 16) | (hb & 0xffff0000u);
        lw[i] = la | (lb << 16);
    }
    hq = make_uint4(hw[0], hw[1], hw[2], hw[3]);
    lq = make_uint4(lw[0], lw[1], lw[2], lw[3]);
}

// ---------------- twiddle table ----------------
__global__ void k_table(float2* __restrict__ tab) {
    int t = threadIdx.x;
    double a = (6.283185307179586476925286766559 / 256.0) * (double)t;
    tab[t] = make_float2((float)cos(a), (float)sin(a));
}

// ---------------- once: trig, trigFT, w1T, wwT_all ----------------
__global__ void k_prep0(const float2* __restrict__ tab, const float* __restrict__ fc1w,
                        const float* __restrict__ ww,
                        float* __restrict__ trig, float* __restrict__ trigFT,
                        float* __restrict__ w1T, float* __restrict__ wwT_all) {
    int blk = blockIdx.x, t = threadIdx.x;
    if (blk < 32) {                    // trig[kk][x]: cos kk<16, +sin kk>=16
        int k = blk & 15;
        float2 e = tab[(k * t) & 255];
        trig[blk * 256 + t] = (blk < 16) ? e.x : e.y;
    } else if (blk < 64) {             // trigFT[y][kk]: cos kk<16, -sin kk>=16
        int f = (blk - 32) * 256 + t;
        int y = f >> 5, kk = f & 31;
        float2 e = tab[((kk & 15) * y) & 255];
        trigFT[f] = (kk < 16) ? e.x : -e.y;
    } else if (blk < 96) {             // w1T[i][m] = fc1w[m][i]
        int f = (blk - 64) * 256 + t;
        int i = f >> 7, m = f & 127;
        w1T[f] = fc1w[m * 64 + i];
    } else {                           // wwT_all[d][i][o] = ww[d][o][i]
        int f = (blk - 96) * 256 + t;
        int d = f >> 12, r = f & 4095;
        int i = r >> 6, o = r & 63;
        wwT_all[f] = ww[d * 4096 + o * 64 + i];
    }
}

// ---------------- once: split-bf16 A-fragments of the y-DFT matrix ----------------
__global__ void k_prep_et(const float2* __restrict__ tab,
                          uint4* __restrict__ ETh, uint4* __restrict__ ETl) {
    int c = blockIdx.x * 256 + threadIdx.x;
    if (c >= 1024) return;
    int ph = c >> 7, kc = (c >> 5) & 3, m = c & 31;
    float v[8];
#pragma unroll
    for (int j = 0; j < 8; ++j) {
        int y = ph * 32 + kc * 8 + j;
        float2 e = tab[((m & 15) * y) & 255];
        v[j] = (m < 16) ? e.x : -e.y;
    }
    uint4 hq, lq;
    split_pack8(v, hq, lq);
    ETh[c] = hq; ETl[c] = lq;
}

// ---------------- fc0 ----------------
__global__ void k_fc0(const float* __restrict__ x, const float* __restrict__ w,
                      const float* __restrict__ bias, float* __restrict__ h) {
    int p = blockIdx.x * 256 + threadIdx.x;
    int b = p >> 16, pix = p & 65535;
    float x0 = x[(b * 3 + 0) * HW + pix];
    float x1 = x[(b * 3 + 1) * HW + pix];
    float x2 = x[(b * 3 + 2) * HW + pix];
    for (int o = 0; o < C; ++o) {
        float v = bias[o];
        v = fmaf(w[o * 3 + 0], x0, v);
        v = fmaf(w[o * 3 + 1], x1, v);
        v = fmaf(w[o * 3 + 2], x2, v);
        h[(b * C + o) * HW + pix] = v;
    }
}

// ---------------- forward y-DFT: split-bf16 MFMA GEMM + prefetch ----------------
// R16: rolling register prefetch of next phase's h rows; lgkm-only barriers keep
// the prefetch vmcnt in flight across the phase boundary.
__global__ __launch_bounds__(256, 4)
void k_fwd_y(const float* __restrict__ h, const uint4* __restrict__ ETh,
             const uint4* __restrict__ ETl, float* __restrict__ T1F) {
    __shared__ uint4 sBh[512], sBl[512];   // [kc(4)][x(128)] 8 KB each
    int blk = blockIdx.x;                  // bc(512) * xh(2), xh fastest
    int xh = blk & 1, bc = blk >> 1;
    int x0 = xh * 128;
    int t = threadIdx.x;
    int xs = t & 127, half = t >> 7;       // staging: x=xs, k-run half*16..+15
    int w = t >> 6, l = t & 63;            // wave w owns x in [w*32, w*32+32)
    int lr = l & 15, lq = l >> 4;
    f32x4 acc[2][2];
#pragma unroll
    for (int u = 0; u < 2; ++u)
#pragma unroll
        for (int xt = 0; xt < 2; ++xt) {
            acc[u][xt][0] = 0.f; acc[u][xt][1] = 0.f;
            acc[u][xt][2] = 0.f; acc[u][xt][3] = 0.f;
        }
    const float* hb = h + (size_t)bc * HW + (half * 16) * 256 + x0 + xs;
    float v0[16], v1[16];
    auto loadv = [&](float* vv, int ph) {
        const float* src = hb + ph * 32 * 256;
#pragma unroll
        for (int kk = 0; kk < 16; ++kk) vv[kk] = src[kk * 256];
    };
    auto stage = [&](const float* vv) {
#pragma unroll
        for (int c2 = 0; c2 < 2; ++c2) {
            uint4 hq4, lq4;
            split_pack8(vv + c2 * 8, hq4, lq4);
            int cell = (half * 2 + c2) * 128 + xs;
            sBh[cell] = hq4; sBl[cell] = lq4;
        }
    };
    loadv(v0, 0);
#pragma unroll
    for (int ph = 0; ph < 8; ++ph) {
        const float* cur = (ph & 1) ? v1 : v0;
        float* nxt = (ph & 1) ? v0 : v1;
        if (ph < 7) loadv(nxt, ph + 1);
        stage(cur);
        bar_lgkm();
        bf16x8 Ah[2], Al[2];
#pragma unroll
        for (int u = 0; u < 2; ++u) {
            int ci = ph * 128 + lq * 32 + u * 16 + lr;
            Ah[u] = __builtin_bit_cast(bf16x8, ETh[ci]);
            Al[u] = __builtin_bit_cast(bf16x8, ETl[ci]);
        }
#pragma unroll
        for (int xt = 0; xt < 2; ++xt) {
            bf16x8 Bh = __builtin_bit_cast(bf16x8, sBh[lq * 128 + w * 32 + xt * 16 + lr]);
            bf16x8 Bl = __builtin_bit_cast(bf16x8, sBl[lq * 128 + w * 32 + xt * 16 + lr]);
#pragma unroll
            for (int u = 0; u < 2; ++u) {
                acc[u][xt] = __builtin_amdgcn_mfma_f32_16x16x32_bf16(Ah[u], Bh, acc[u][xt], 0, 0, 0);
                acc[u][xt] = __builtin_amdgcn_mfma_f32_16x16x32_bf16(Ah[u], Bl, acc[u][xt], 0, 0, 0);
                acc[u][xt] = __builtin_amdgcn_mfma_f32_16x16x32_bf16(Al[u], Bh, acc[u][xt], 0, 0, 0);
            }
        }
        bar_lgkm();
    }
    // D: row = u*16 + lq*4 + g (mode kk), col = x0 + w*32 + xt*16 + lr
#pragma unroll
    for (int u = 0; u < 2; ++u)
#pragma unroll
        for (int xt = 0; xt < 2; ++xt)
#pragma unroll
            for (int g = 0; g < 4; ++g)
                T1F[(size_t)bc * 8192 + (u * 16 + lq * 4 + g) * 256 + x0 + w * 32 + xt * 16 + lr] =
                    acc[u][xt][g];
}

// ---------------- forward x-DFT (unchanged from R12) ----------------
__global__ __launch_bounds__(256, 2)
void k_fwd_x(const float* __restrict__ T1F, const float* __restrict__ trig,
             float2* __restrict__ X) {
    __shared__ float sT[32 * 260];
    __shared__ float sG[32 * 260];
    int bc = blockIdx.x, t = threadIdx.x;
#pragma unroll
    for (int p = 0; p < 8; ++p) {
        int f = t + p * 256;
        int row = f >> 6, seg = f & 63;
        ((float4*)(sT + row * 260))[seg] = *(const float4*)(T1F + (size_t)bc * 8192 + f * 4);
        ((float4*)(sG + row * 260))[seg] = *(const float4*)(trig + row * 256 + seg * 4);
    }
    __syncthreads();
    int ky = t >> 4, kx = t & 15;
    const float* Tr = sT + ky * 260;
    const float* Ti = sT + (16 + ky) * 260;
    const float* Cs = sG + kx * 260;
    const float* Sn = sG + (16 + kx) * 260;
    float xr0 = 0.f, xi0 = 0.f, xr1 = 0.f, xi1 = 0.f;
    for (int q = 0; q < 64; q += 2) {
        float4 tr = *(const float4*)(Tr + q * 4);
        float4 ti = *(const float4*)(Ti + q * 4);
        float4 cs = *(const float4*)(Cs + q * 4);
        float4 sn = *(const float4*)(Sn + q * 4);
        xr0 = fmaf(tr.x, cs.x, xr0); xr0 = fmaf(ti.x, sn.x, xr0);
        xi0 = fmaf(ti.x, cs.x, xi0); xi0 = fmaf(-tr.x, sn.x, xi0);
        xr0 = fmaf(tr.y, cs.y, xr0); xr0 = fmaf(ti.y, sn.y, xr0);
        xi0 = fmaf(ti.y, cs.y, xi0); xi0 = fmaf(-tr.y, sn.y, xi0);
        xr0 = fmaf(tr.z, cs.z, xr0); xr0 = fmaf(ti.z, sn.z, xr0);
        xi0 = fmaf(ti.z, cs.z, xi0); xi0 = fmaf(-tr.z, sn.z, xi0);
        xr0 = fmaf(tr.w, cs.w, xr0); xr0 = fmaf(ti.w, sn.w, xr0);
        xi0 = fmaf(ti.w, cs.w, xi0); xi0 = fmaf(-tr.w, sn.w, xi0);
        float4 tr1 = *(const float4*)(Tr + q * 4 + 4);
        float4 ti1 = *(const float4*)(Ti + q * 4 + 4);
        float4 cs1 = *(const float4*)(Cs + q * 4 + 4);
        float4 sn1 = *(const float4*)(Sn + q * 4 + 4);
        xr1 = fmaf(tr1.x, cs1.x, xr1); xr1 = fmaf(ti1.x, sn1.x, xr1);
        xi1 = fmaf(ti1.x, cs1.x, xi1); xi1 = fmaf(-tr1.x, sn1.x, xi1);
        xr1 = fmaf(tr1.y, cs1.y, xr1); xr1 = fmaf(ti1.y, sn1.y, xr1);
        xi1 = fmaf(ti1.y, cs1.y, xi1); xi1 = fmaf(-tr1.y, sn1.y, xi1);
        xr1 = fmaf(tr1.z, cs1.z, xr1); xr1 = fmaf(ti1.z, sn1.z, xr1);
        xi1 = fmaf(ti1.z, cs1.z, xi1); xi1 = fmaf(-tr1.z, sn1.z, xi1);
        xr1 = fmaf(tr1.w, cs1.w, xr1); xr1 = fmaf(ti1.w, sn1.w, xr1);
        xi1 = fmaf(ti1.w, cs1.w, xi1); xi1 = fmaf(-tr1.w, sn1.w, xi1);
    }
    X[bc * 256 + t] = make_float2(xr0 + xr1, xi0 + xi1);
}

// ---------------- mode mixing (unchanged) ----------------
__global__ __launch_bounds__(256, 2)
void k_mix(const float2* __restrict__ X, const float* __restrict__ wre,
           const float* __restrict__ wim, float2* __restrict__ Y) {
    int o = blockIdx.x >> 2;
    int bq = blockIdx.x & 3;
    int m = threadIdx.x;
    int b0 = bq * 2, b1 = bq * 2 + 1;
    float yr0 = 0.f, yi0 = 0.f, yr1 = 0.f, yi1 = 0.f;
    for (int i = 0; i < C; ++i) {
        float wr = wre[(i * C + o) * 256 + m];
        float wi = wim[(i * C + o) * 256 + m];
        float2 x0 = X[(b0 * C + i) * 256 + m];
        float2 x1 = X[(b1 * C + i) * 256 + m];
        yr0 = fmaf(x0.x, wr, fmaf(-x0.y, wi, yr0));
        yi0 = fmaf(x0.x, wi, fmaf(x0.y, wr, yi0));
        yr1 = fmaf(x1.x, wr, fmaf(-x1.y, wi, yr1));
        yi1 = fmaf(x1.x, wi, fmaf(x1.y, wr, yi1));
    }
    Y[(b0 * C + o) * 256 + m] = make_float2(yr0, yi0);
    Y[(b1 * C + o) * 256 + m] = make_float2(yr1, yi1);
}

// ---------------- fused inverse-y + Gq production (unchanged) ----------------
__global__ __launch_bounds__(256, 2)
void k_invy(const float2* __restrict__ Y, const float2* __restrict__ tab,
            float* __restrict__ Gq) {
    __shared__ float2 st[256];
    int blk = blockIdx.x;              // 8b x 4pg x 16yt
    int yt = blk & 15, pg = (blk >> 4) & 3, b = blk >> 6;
    int t = threadIdx.x;
    st[t] = tab[t];
    int o = t & 63, kx = pg * 4 + (t >> 6);
    __syncthreads();
    float sc = (kx == 0 ? 1.0f : 2.0f) * (1.0f / 65536.0f);
    float yr[16], yi[16];
    const float2* yp = Y + (size_t)(b * 64 + o) * 256 + kx;
#pragma unroll
    for (int ky = 0; ky < 16; ++ky) {
        float2 v = yp[ky * 16];
        yr[ky] = v.x * sc;
        yi[ky] = v.y * sc;
    }
    int y0 = yt * 16;
    for (int yy = 0; yy < 16; ++yy) {
        int y = y0 + yy;
        float re = 0.f, im = 0.f;
#pragma unroll
        for (int ky = 0; ky < 16; ++ky) {
            float2 e = st[(ky * y) & 255];
            re = fmaf(yr[ky], e.x, re);
            re = fmaf(-yi[ky], e.y, re);
            im = fmaf(yr[ky], e.y, im);
            im = fmaf(yi[ky], e.x, im);
        }
        float* gp = Gq + (size_t)(b * 256 + y) * 32 * 64 + o;
        gp[kx * 64] = re;
        gp[(16 + kx) * 64] = -im;
    }
}

// ---------------- k_final: split-bf16 MFMA augmented GEMM + prefetch ----------------
__global__ __launch_bounds__(256, 4)
void k_final(float* __restrict__ h, const float* __restrict__ Gq,
             const float* __restrict__ wwT, const float* __restrict__ wb,
             const float* __restrict__ trig) {
    __shared__ uint4 sHh[512], sHl[512];   // [kc(4)][x(128)] 16 KB
    __shared__ uint4 sWh[256], sWl[256];   // [kc(4)][o(64)]   8 KB
    int blk = blockIdx.x;              // b(8) * y(256) * xq(2), xq fastest
    int xq = blk & 1, y = (blk >> 1) & 255, b = blk >> 9;
    int x0 = xq * 128;
    int t = threadIdx.x;
    int xs = t & 127, half = t >> 7;   // H staging: thread owns x=xs, k-run half*16..+15
    int os = t & 63, q = t >> 6;       // W staging: thread owns o=os, k-run q*8..+7
    int w = t >> 6, l = t & 63;        // wave w owns o-rows [w*16, w*16+16)
    int lr = l & 15, lq = l >> 4;
    f32x4 acc[8];
    {
        int ob = w * 16 + lq * 4;      // D row = (l>>4)*4+g  [m89-verified]
        f32x4 ini;
        ini[0] = wb[ob]; ini[1] = wb[ob + 1]; ini[2] = wb[ob + 2]; ini[3] = wb[ob + 3];
#pragma unroll
        for (int xt = 0; xt < 8; ++xt) acc[xt] = ini;
    }
    float vh0[16], vh1[16], vw0[8], vw1[8];
    auto loadH = [&](float* vv, int ph) {
        const float* src; size_t str;
        if (ph < 2) {
            src = h + (size_t)(b * 64 + ph * 32 + half * 16) * HW + y * 256 + x0 + xs;
            str = HW;
        } else {
            src = trig + (half * 16) * 256 + x0 + xs;
            str = 256;
        }
#pragma unroll
        for (int kk = 0; kk < 16; ++kk) vv[kk] = src[(size_t)kk * str];
    };
    auto loadW = [&](float* vv, int ph) {
        const float* src = (ph < 2)
            ? (wwT + (ph * 32 + q * 8) * 64 + os)
            : (Gq + ((size_t)(b * 256 + y) * 32 + q * 8) * 64 + os);
#pragma unroll
        for (int kk = 0; kk < 8; ++kk) vv[kk] = src[kk * 64];
    };
    loadH(vh0, 0); loadW(vw0, 0);
#pragma unroll
    for (int ph = 0; ph < 3; ++ph) {
        const float* cH = (ph & 1) ? vh1 : vh0;
        float* nH = (ph & 1) ? vh0 : vh1;
        const float* cW = (ph & 1) ? vw1 : vw0;
        float* nW = (ph & 1) ? vw0 : vw1;
        if (ph < 2) { loadH(nH, ph + 1); loadW(nW, ph + 1); }
#pragma unroll
        for (int c2 = 0; c2 < 2; ++c2) {
            uint4 hq4, lq4;
            split_pack8(cH + c2 * 8, hq4, lq4);
            int cell = (half * 2 + c2) * 128 + xs;
            sHh[cell] = hq4; sHl[cell] = lq4;
        }
        {
            uint4 hq4, lq4;
            split_pack8(cW, hq4, lq4);
            int cell = q * 64 + os;
            sWh[cell] = hq4; sWl[cell] = lq4;
        }
        bar_lgkm();
        // A frag: lane holds W[o = w*16 + (l&15)][k = (l>>4)*8 + j]
        bf16x8 Ah = __builtin_bit_cast(bf16x8, sWh[lq * 64 + w * 16 + lr]);
        bf16x8 Al = __builtin_bit_cast(bf16x8, sWl[lq * 64 + w * 16 + lr]);
#pragma unroll
        for (int xt = 0; xt < 8; ++xt) {
            // B frag: lane holds H[k = (l>>4)*8 + j][x = xt*16 + (l&15)]
            bf16x8 Bh = __builtin_bit_cast(bf16x8, sHh[lq * 128 + xt * 16 + lr]);
            bf16x8 Bl = __builtin_bit_cast(bf16x8, sHl[lq * 128 + xt * 16 + lr]);
            acc[xt] = __builtin_amdgcn_mfma_f32_16x16x32_bf16(Ah, Bh, acc[xt], 0, 0, 0);
            acc[xt] = __builtin_amdgcn_mfma_f32_16x16x32_bf16(Ah, Bl, acc[xt], 0, 0, 0);
            acc[xt] = __builtin_amdgcn_mfma_f32_16x16x32_bf16(Al, Bh, acc[xt], 0, 0, 0);
        }
        bar_lgkm();
    }
    // epilogue: relu + store (16-lane x 64B segments per o-row)
#pragma unroll
    for (int g = 0; g < 4; ++g) {
        int o = w * 16 + lq * 4 + g;
        float* dst = h + (size_t)(b * 64 + o) * HW + y * 256 + x0 + lr;
#pragma unroll
        for (int xt = 0; xt < 8; ++xt)
            dst[xt * 16] = fmaxf(acc[xt][g], 0.f);
    }
}

// ---------------- fc1+fc2: split-bf16 MFMA GEMM + in-reg fc2 reduce + prefetch ----------------
// R16: prefetch H-side only (acc[2][8] = 64 VGPR; full prefetch would exceed the
// 128-reg cap at 4 blocks/CU). w1T is 8 KB L2-hot; its latency is small.
__global__ __launch_bounds__(256, 4)
void k_fc12(const float* __restrict__ h, const float* __restrict__ w1T,
            const float* __restrict__ b1, const float* __restrict__ w2,
            const float* __restrict__ b2, float* __restrict__ out) {
    __shared__ uint4 sHh[512], sHl[512];   // [kc(4)][x(128)] 16 KB
    __shared__ uint4 sWh[512], sWl[512];   // [kc(4)][m(128)] 16 KB
    int blk = blockIdx.x;                  // b(8) * y(256) * xq(2), xq fastest
    int xq = blk & 1, y = (blk >> 1) & 255, b = blk >> 9;
    int x0 = xq * 128;
    int t = threadIdx.x;
    int xs = t & 127, half = t >> 7;
    int w = t >> 6, l = t & 63;
    int lr = l & 15, lq = l >> 4;
    int mb = w * 32;
    f32x4 acc[2][8];
#pragma unroll
    for (int u = 0; u < 2; ++u) {
        int m0 = mb + u * 16 + lq * 4;
        f32x4 ini;
        ini[0] = b1[m0]; ini[1] = b1[m0 + 1]; ini[2] = b1[m0 + 2]; ini[3] = b1[m0 + 3];
#pragma unroll
        for (int xt = 0; xt < 8; ++xt) acc[u][xt] = ini;
    }
    float vh0[16], vh1[16];
    auto loadH = [&](float* vv, int ph) {
        const float* src = h + (size_t)(b * 64 + ph * 32 + half * 16) * HW + y * 256 + x0 + xs;
#pragma unroll
        for (int kk = 0; kk < 16; ++kk) vv[kk] = src[(size_t)kk * HW];
    };
    loadH(vh0, 0);
#pragma unroll
    for (int ph = 0; ph < 2; ++ph) {
        const float* cH = (ph & 1) ? vh1 : vh0;
        float* nH = (ph & 1) ? vh0 : vh1;
        if (ph < 1) loadH(nH, ph + 1);
#pragma unroll
        for (int c2 = 0; c2 < 2; ++c2) {
            uint4 hq4, lq4;
            split_pack8(cH + c2 * 8, hq4, lq4);
            int cell = (half * 2 + c2) * 128 + xs;
            sHh[cell] = hq4; sHl[cell] = lq4;
        }
        {   // W1: 32 c-rows x 128 m   (w1T[i][m], stride 128 over i)
            const float* src = w1T + (ph * 32 + half * 16) * 128 + xs;
            float v[16];
#pragma unroll
            for (int kk = 0; kk < 16; ++kk) v[kk] = src[kk * 128];
#pragma unroll
            for (int c2 = 0; c2 < 2; ++c2) {
                uint4 hq4, lq4;
                split_pack8(v + c2 * 8, hq4, lq4);
                int cell = (half * 2 + c2) * 128 + xs;
                sWh[cell] = hq4; sWl[cell] = lq4;
            }
        }
        bar_lgkm();
        bf16x8 Ah[2], Al[2];
#pragma unroll
        for (int u = 0; u < 2; ++u) {
            Ah[u] = __builtin_bit_cast(bf16x8, sWh[lq * 128 + mb + u * 16 + lr]);
            Al[u] = __builtin_bit_cast(bf16x8, sWl[lq * 128 + mb + u * 16 + lr]);
        }
#pragma unroll
        for (int xt = 0; xt < 8; ++xt) {
            bf16x8 Bh = __builtin_bit_cast(bf16x8, sHh[lq * 128 + xt * 16 + lr]);
            bf16x8 Bl = __builtin_bit_cast(bf16x8, sHl[lq * 128 + xt * 16 + lr]);
#pragma unroll
            for (int u = 0; u < 2; ++u) {
                acc[u][xt] = __builtin_amdgcn_mfma_f32_16x16x32_bf16(Ah[u], Bh, acc[u][xt], 0, 0, 0);
                acc[u][xt] = __builtin_amdgcn_mfma_f32_16x16x32_bf16(Ah[u], Bl, acc[u][xt], 0, 0, 0);
                acc[u][xt] = __builtin_amdgcn_mfma_f32_16x16x32_bf16(Al[u], Bh, acc[u][xt], 0, 0, 0);
            }
        }
        bar_lgkm();
    }
    // relu + fc2 partials: lane holds D[m = mb+u*16+lq*4+g][x = xt*16+lr]
    float pj[3][8];
#pragma unroll
    for (int j = 0; j < 3; ++j)
#pragma unroll
        for (int xt = 0; xt < 8; ++xt) pj[j][xt] = 0.f;
#pragma unroll
    for (int u = 0; u < 2; ++u)
#pragma unroll
        for (int g = 0; g < 4; ++g) {
            int m = mb + u * 16 + lq * 4 + g;
            float w20 = w2[m], w21 = w2[NMLP + m], w22 = w2[2 * NMLP + m];
#pragma unroll
            for (int xt = 0; xt < 8; ++xt) {
                float r = fmaxf(acc[u][xt][g], 0.f);
                pj[0][xt] = fmaf(w20, r, pj[0][xt]);
                pj[1][xt] = fmaf(w21, r, pj[1][xt]);
                pj[2][xt] = fmaf(w22, r, pj[2][xt]);
            }
        }
    // reduce lane-quadrants (m-subrows) via shfl, then the 4 waves via LDS
#pragma unroll
    for (int j = 0; j < 3; ++j)
#pragma unroll
        for (int xt = 0; xt < 8; ++xt) {
            float v = pj[j][xt];
            v += __shfl_xor(v, 16);
            v += __shfl_xor(v, 32);
            pj[j][xt] = v;
        }
    float* part = (float*)sHh;   // 4*3*128 floats = 6 KB; all GEMM LDS reads done
    if (lq == 0) {
#pragma unroll
        for (int j = 0; j < 3; ++j)
#pragma unroll
            for (int xt = 0; xt < 8; ++xt)
                part[(w * 3 + j) * 128 + xt * 16 + lr] = pj[j][xt];
    }
    __syncthreads();
#pragma unroll
    for (int r = 0; r < 2; ++r) {
        int idx = t + r * 256;
        if (idx < 384) {
            int j = idx >> 7, xx = idx & 127;
            float s = b2[j];
#pragma unroll
            for (int ww2 = 0; ww2 < 4; ++ww2) s += part[(ww2 * 3 + j) * 128 + xx];
            out[(size_t)(b * 3 + j) * HW + y * 256 + x0 + xx] = s;
        }
    }
}

extern "C" void kernel_launch(void* const* d_in, const int* in_sizes, int n_in,
                              void* d_out, int out_size, void* d_ws, size_t ws_size,
                              hipStream_t stream) {
    const float* x     = (const float*)d_in[0];
    const float* fc0_w = (const float*)d_in[1];
    const float* fc0_b = (const float*)d_in[2];
    const float* swre  = (const float*)d_in[3];
    const float* swim  = (const float*)d_in[4];
    const float* ww    = (const float*)d_in[5];
    const float* wb    = (const float*)d_in[6];
    const float* fc1w  = (const float*)d_in[7];
    const float* fc1b  = (const float*)d_in[8];
    const float* fc2w  = (const float*)d_in[9];
    const float* fc2b  = (const float*)d_in[10];

    float* ws = (float*)d_ws;
    float2* tab    = (float2*)ws;                     // 512 floats
    float*  h      = ws + 512;                        // 33,554,432
    float*  T1F    = ws + 33554944;                   // 4,194,304
    float2* X      = (float2*)(ws + 37749248);        // 262,144 floats
    float2* Y      = (float2*)(ws + 38011392);        // 262,144 floats
    float*  Gq     = ws + 38273536;                   // 4,194,304
    float*  wwT    = ws + 42467840;                   // 16,384
    float*  w1T    = ws + 42484224;                   // 8,192
    float*  trig   = ws + 42492416;                   // 8,192
    float*  trigFT = ws + 42500608;                   // 8,192
    uint4*  ETh    = (uint4*)(ws + 42508800);         // 1024 cells = 16 KB
    uint4*  ETl    = (uint4*)(ws + 42512896);         // 1024 cells = 16 KB

    k_table<<<dim3(1), dim3(256), 0, stream>>>(tab);
    k_prep0<<<dim3(160), dim3(256), 0, stream>>>(tab, fc1w, ww, trig, trigFT, w1T, wwT);
    k_prep_et<<<dim3(4), dim3(256), 0, stream>>>(tab, ETh, ETl);
    k_fc0<<<dim3(2048), dim3(256), 0, stream>>>(x, fc0_w, fc0_b, h);

    for (int d = 0; d < NDEPTH; ++d) {
        k_fwd_y<<<dim3(1024), dim3(256), 0, stream>>>(h, ETh, ETl, T1F);
        k_fwd_x<<<dim3(512), dim3(256), 0, stream>>>(T1F, trig, X);
        k_mix<<<dim3(256), dim3(256), 0, stream>>>(X, swre + (size_t)d * C * C * 256,
                                                   swim + (size_t)d * C * C * 256, Y);
        k_invy<<<dim3(512), dim3(256), 0, stream>>>(Y, tab, Gq);
        k_final<<<dim3(4096), dim3(256), 0, stream>>>(h, Gq, wwT + d * 4096, wb + d * C, trig);
    }
    k_fc12<<<dim3(4096), dim3(256), 0, stream>>>(h, w1T, fc1b, fc2w, fc2b, (float*)d_out);
}